// Round 2
// baseline (491.966 us; speedup 1.0000x reference)
//
#include <hip/hip_runtime.h>
#include <hip/hip_bf16.h>

typedef __attribute__((ext_vector_type(8))) short bf16x8;
typedef __attribute__((ext_vector_type(4))) float f32x4;

#define HID 512
#define NB 32
#define SEQL 4096
#define BM 64
#define BK 32
#define NKC 16          // 512/32 k-chunks
#define NBLK 2048       // 131072 rows / 64

// workspace layout (bytes)
#define WS_BP    0              // packed bf16 W_enc: 512 KB
#define WS_DPROJ (512*1024)     // fp32 32x512: 64 KB
#define WS_SUM   (576*1024)     // fp32 32: 128 B

__device__ __forceinline__ short f2bf(float f) {
    unsigned u = __float_as_uint(f);
    unsigned r = (u + 0x7fffu + ((u >> 16) & 1u)) >> 16;   // RNE
    return (short)r;
}

__device__ __forceinline__ float fast_tanh(float x) {
    float e = __expf(2.0f * x);
    float r = __builtin_amdgcn_rcpf(e + 1.0f);
    return 1.0f - 2.0f * r;
}

__device__ __forceinline__ void async16(const void* g, void* l) {
    __builtin_amdgcn_global_load_lds((__attribute__((address_space(1))) void*)(g),
                                     (__attribute__((address_space(3))) void*)(l),
                                     16, 0, 0);
}

// ---------------------------------------------------------------------------
// K_pre: fused (a) W_enc pack fp32->bf16 B-frag layout, (b) dproj GEMV,
// (c) zero-init of context accumulator + expsum accumulator.
// grid = 256 blocks x 256 threads.
// ---------------------------------------------------------------------------
__global__ void k_pre(const float* __restrict__ We, short* __restrict__ Bp,
                      const float* __restrict__ dec, const float* __restrict__ Wd,
                      const float* __restrict__ be, const float* __restrict__ bd,
                      float* __restrict__ dproj, float* __restrict__ out,
                      float* __restrict__ sumacc) {
    const int blk = blockIdx.x, t = threadIdx.x;
    if (blk < 128) {
        // pack: Bp[kc][nt][lane][j] = We[kc*32 + (lane>>4)*8 + j][nt*16 + (lane&15)]
        int tid  = blk * 256 + t;
        int lane = tid & 63;
        int nt   = (tid >> 6) & 31;
        int kc   = tid >> 11;
        int k0   = kc * 32 + (lane >> 4) * 8;
        int n    = nt * 16 + (lane & 15);
        bf16x8 v;
#pragma unroll
        for (int j = 0; j < 8; ++j) v[j] = f2bf(We[(size_t)(k0 + j) * HID + n]);
        *(bf16x8*)&Bp[(size_t)tid * 8] = v;
    } else if (blk < 192) {
        int bid = blk - 128;
        if (bid == 0 && t < NB) sumacc[t] = 0.f;
        int kl = t & 31, bq = t >> 5;
        int k  = (bid & 15) * 32 + kl;
        int b  = (bid >> 4) * 8 + bq;
        float a = be[k] + bd[k];
        const float* dr = dec + (size_t)b * HID;
#pragma unroll 8
        for (int h = 0; h < HID; ++h)
            a += dr[h] * Wd[(size_t)h * HID + k];
        dproj[(size_t)b * HID + k] = a;
    } else {
        // zero context region of d_out: 64 blocks x 256 = 16384 floats
        out[(blk - 192) * 256 + t] = 0.f;
    }
}

// ---------------------------------------------------------------------------
// K_main: 64 rows x 512 cols enc_proj via bf16 MFMA, double-buffered LDS,
// fused tanh*W_v -> score -> p=exp(score) -> partial expsum + partial context.
// ---------------------------------------------------------------------------
__global__ __launch_bounds__(256, 2)
void k_main(const float* __restrict__ E, const short* __restrict__ Bp,
            const float* __restrict__ dproj, const float* __restrict__ Wv,
            float* __restrict__ out, float* __restrict__ sumacc) {
    __shared__ short As[2][BM][BK + 8];   // 2 x 64 x 40 shorts = 10 KB
    __shared__ short Bs[2][BK * HID];     // 2 x 32 KB
    __shared__ float fbuf[640];
    __shared__ float pbuf[BM];

    const int tid  = threadIdx.x;
    const int wave = tid >> 6, lane = tid & 63;
    const int quad = lane >> 4, l15 = lane & 15;
    const int bid  = blockIdx.x;
    const int row0 = bid * BM;           // global row = b*4096 + s
    const int b    = bid >> 6;           // 64 blocks per batch

    f32x4 acc[4][8];
#pragma unroll
    for (int r = 0; r < 4; ++r)
#pragma unroll
        for (int c = 0; c < 8; ++c) acc[r][c] = (f32x4){0.f, 0.f, 0.f, 0.f};

    // A staging: thread t -> row t>>2, k-eighth t&3 (8 floats)
    const int arow = tid >> 2, akq = tid & 3;
    const float* aptr = E + (size_t)(row0 + arow) * HID + akq * 8;

    // ---- prologue: stage chunk 0 into buffer 0 ----
    {
        const short* bsrc = Bp;
#pragma unroll
        for (int i = 0; i < 8; ++i) {
            int off = (i * 4 + wave) * 512;
            async16(bsrc + off + lane * 8, &Bs[0][off]);
        }
        float4 a0 = *(const float4*)(aptr);
        float4 a1 = *(const float4*)(aptr + 4);
        bf16x8 av;
        av[0] = f2bf(a0.x); av[1] = f2bf(a0.y); av[2] = f2bf(a0.z); av[3] = f2bf(a0.w);
        av[4] = f2bf(a1.x); av[5] = f2bf(a1.y); av[6] = f2bf(a1.z); av[7] = f2bf(a1.w);
        *(bf16x8*)&As[0][arow][akq * 8] = av;
    }

    int cur = 0;
    for (int kc = 0; kc < NKC; ++kc) {
        const int nxt = cur ^ 1;
        // barrier: drains B-async(cur) (issued one compute-phase ago) + A writes(cur)
        __syncthreads();

        // ---- issue prefetch of chunk kc+1 AFTER the barrier ----
        float4 a0, a1;
        const bool pf = (kc + 1 < NKC);
        if (pf) {
            a0 = *(const float4*)(aptr + (kc + 1) * 32);
            a1 = *(const float4*)(aptr + (kc + 1) * 32 + 4);
            const short* bsrc = Bp + (size_t)(kc + 1) * 16384;
#pragma unroll
            for (int i = 0; i < 8; ++i) {
                int off = (i * 4 + wave) * 512;
                async16(bsrc + off + lane * 8, &Bs[nxt][off]);
            }
        }

        // ---- compute on buffer cur: wave tile 64 rows x 128 cols ----
        bf16x8 fa[4];
#pragma unroll
        for (int r = 0; r < 4; ++r) fa[r] = *(bf16x8*)&As[cur][r * 16 + l15][quad * 8];
#pragma unroll
        for (int c = 0; c < 8; ++c) {
            int nt = wave * 8 + c;
            bf16x8 fb = *(bf16x8*)&Bs[cur][(nt * 64 + lane) * 8];
#pragma unroll
            for (int r = 0; r < 4; ++r)
                acc[r][c] = __builtin_amdgcn_mfma_f32_16x16x32_bf16(fa[r], fb, acc[r][c], 0, 0, 0);
        }

        // ---- convert + LDS-stage prefetched A (load had a full phase to land) ----
        if (pf) {
            bf16x8 av;
            av[0] = f2bf(a0.x); av[1] = f2bf(a0.y); av[2] = f2bf(a0.z); av[3] = f2bf(a0.w);
            av[4] = f2bf(a1.x); av[5] = f2bf(a1.y); av[6] = f2bf(a1.z); av[7] = f2bf(a1.w);
            *(bf16x8*)&As[nxt][arow][akq * 8] = av;
        }
        cur = nxt;
    }

    // ---- epilogue a: score = sum_col tanh(acc + dproj[col]) * Wv[col] ----
    float part[4][4];
#pragma unroll
    for (int r = 0; r < 4; ++r)
#pragma unroll
        for (int g = 0; g < 4; ++g) part[r][g] = 0.f;
    const float* dp = dproj + (size_t)b * HID;
#pragma unroll
    for (int c = 0; c < 8; ++c) {
        int col = wave * 128 + c * 16 + l15;
        float dv = dp[col];
        float wv = Wv[col];
#pragma unroll
        for (int r = 0; r < 4; ++r)
#pragma unroll
            for (int g = 0; g < 4; ++g)
                part[r][g] += fast_tanh(acc[r][c][g] + dv) * wv;
    }
#pragma unroll
    for (int r = 0; r < 4; ++r)
#pragma unroll
        for (int g = 0; g < 4; ++g) {
            float v = part[r][g];
            v += __shfl_xor(v, 1); v += __shfl_xor(v, 2);
            v += __shfl_xor(v, 4); v += __shfl_xor(v, 8);
            part[r][g] = v;
        }
    if (l15 == 0) {
#pragma unroll
        for (int r = 0; r < 4; ++r)
#pragma unroll
            for (int g = 0; g < 4; ++g)
                fbuf[wave * 64 + r * 16 + quad * 4 + g] = part[r][g];
    }
    __syncthreads();
    if (tid < 64) {
        float s  = fbuf[tid] + fbuf[64 + tid] + fbuf[128 + tid] + fbuf[192 + tid];
        float pv = __expf(s);           // unnormalized; b_v cancels in softmax
        pbuf[tid] = pv;
        out[(size_t)NB * HID + row0 + tid] = pv;
        float t2 = pv;
        t2 += __shfl_xor(t2, 1);  t2 += __shfl_xor(t2, 2);  t2 += __shfl_xor(t2, 4);
        t2 += __shfl_xor(t2, 8);  t2 += __shfl_xor(t2, 16); t2 += __shfl_xor(t2, 32);
        if (tid == 0) atomicAdd(&sumacc[b], t2);
    }
    __syncthreads();

    // ---- epilogue b: partial context = sum_rows pv * E[row,:] (L2/L3-hot re-read) ----
    const int hq = tid & 127, rh = tid >> 7;
    const float4* E4 = (const float4*)E;
    size_t cbase = (size_t)(row0 + rh * 32) * (HID / 4) + hq;
    float4 ca = {0.f, 0.f, 0.f, 0.f};
#pragma unroll 4
    for (int rr = 0; rr < 32; ++rr) {
        float w  = pbuf[rh * 32 + rr];
        float4 e = E4[cbase + (size_t)rr * (HID / 4)];
        ca.x += w * e.x; ca.y += w * e.y; ca.z += w * e.z; ca.w += w * e.w;
    }
    if (rh == 1) {
        fbuf[hq] = ca.x; fbuf[128 + hq] = ca.y; fbuf[256 + hq] = ca.z; fbuf[384 + hq] = ca.w;
    }
    __syncthreads();
    if (rh == 0) {
        ca.x += fbuf[hq]; ca.y += fbuf[128 + hq]; ca.z += fbuf[256 + hq]; ca.w += fbuf[384 + hq];
        float* cg = out + (size_t)b * HID + hq * 4;
        atomicAdd(cg + 0, ca.x); atomicAdd(cg + 1, ca.y);
        atomicAdd(cg + 2, ca.z); atomicAdd(cg + 3, ca.w);
    }
}

// ---------------------------------------------------------------------------
// K_finish: normalize in place: context /= sum, weights /= sum
// ---------------------------------------------------------------------------
__global__ void k_finish(float* __restrict__ out, const float* __restrict__ sumacc) {
    int b = blockIdx.x, t = threadIdx.x;
    float rs = 1.0f / sumacc[b];
    for (int i = t; i < HID; i += 256)
        out[(size_t)b * HID + i] *= rs;
    float* ow = out + (size_t)NB * HID + (size_t)b * SEQL;
    for (int i = t; i < SEQL; i += 256)
        ow[i] *= rs;
}

extern "C" void kernel_launch(void* const* d_in, const int* in_sizes, int n_in,
                              void* d_out, int out_size, void* d_ws, size_t ws_size,
                              hipStream_t stream) {
    const float* E   = (const float*)d_in[0];
    const float* dec = (const float*)d_in[1];
    const float* We  = (const float*)d_in[2];
    const float* be  = (const float*)d_in[3];
    const float* Wd  = (const float*)d_in[4];
    const float* bd  = (const float*)d_in[5];
    const float* Wv  = (const float*)d_in[6];
    // d_in[7] = b_v: uniform shift per score -> cancels in softmax
    float* out = (float*)d_out;
    char*  ws  = (char*)d_ws;
    short* Bp     = (short*)(ws + WS_BP);
    float* dproj  = (float*)(ws + WS_DPROJ);
    float* sumacc = (float*)(ws + WS_SUM);

    k_pre<<<256, 256, 0, stream>>>(We, Bp, dec, Wd, be, bd, dproj, out, sumacc);
    k_main<<<NBLK, 256, 0, stream>>>(E, Bp, dproj, Wv, out, sumacc);
    k_finish<<<NB, 256, 0, stream>>>(out, sumacc);
}

// Round 3
// 478.300 us; speedup vs baseline: 1.0286x; 1.0286x over previous
//
#include <hip/hip_runtime.h>
#include <hip/hip_bf16.h>

typedef __attribute__((ext_vector_type(8))) short bf16x8;
typedef __attribute__((ext_vector_type(4))) float f32x4;

#define HID 512
#define NB 32
#define SEQL 4096
#define BM 64
#define BK 32
#define NKC 16          // 512/32 k-chunks
#define NBLK 2048       // 131072 rows / 64

// workspace layout (bytes)
#define WS_BP    0              // packed bf16 W_enc: 512 KB
#define WS_DPROJ (512*1024)     // fp32 32x512: 64 KB
#define WS_SUM   (576*1024)     // fp32 32: 128 B

__device__ __forceinline__ short f2bf(float f) {
    unsigned u = __float_as_uint(f);
    unsigned r = (u + 0x7fffu + ((u >> 16) & 1u)) >> 16;   // RNE
    return (short)r;
}

__device__ __forceinline__ float fast_tanh(float x) {
    float e = __expf(2.0f * x);
    float r = __builtin_amdgcn_rcpf(e + 1.0f);
    return 1.0f - 2.0f * r;
}

__device__ __forceinline__ void async16(const void* g, void* l) {
    __builtin_amdgcn_global_load_lds((__attribute__((address_space(1))) void*)(g),
                                     (__attribute__((address_space(3))) void*)(l),
                                     16, 0, 0);
}

// ---------------------------------------------------------------------------
// K_pre: fused (a) W_enc pack fp32->bf16 B-frag layout [blk 0..127],
// (b) dproj GEMV, 8-way h-parallel [blk 128..639], (c) zero-init [blk 640..703]
// ---------------------------------------------------------------------------
__global__ void k_pre(const float* __restrict__ We, short* __restrict__ Bp,
                      const float* __restrict__ dec, const float* __restrict__ Wd,
                      const float* __restrict__ be, const float* __restrict__ bd,
                      float* __restrict__ dproj, float* __restrict__ out,
                      float* __restrict__ sumacc) {
    const int blk = blockIdx.x, t = threadIdx.x;
    if (blk < 128) {
        // pack: Bp[kc][nt][lane][j] = We[kc*32 + (lane>>4)*8 + j][nt*16 + (lane&15)]
        int tid  = blk * 256 + t;
        int lane = tid & 63;
        int nt   = (tid >> 6) & 31;
        int kc   = tid >> 11;
        int k0   = kc * 32 + (lane >> 4) * 8;
        int n    = nt * 16 + (lane & 15);
        bf16x8 v;
#pragma unroll
        for (int j = 0; j < 8; ++j) v[j] = f2bf(We[(size_t)(k0 + j) * HID + n]);
        *(bf16x8*)&Bp[(size_t)tid * 8] = v;
    } else if (blk < 640) {
        __shared__ float red[8][33];
        int bid2 = blk - 128;
        int b  = bid2 >> 4, kg = bid2 & 15;     // 32 batches x 16 k-groups
        int kl = t & 31,    hc = t >> 5;        // 32 k-cols x 8 h-chunks
        int k  = kg * 32 + kl;
        const float* dr = dec + (size_t)b * HID;
        float a = 0.f;
#pragma unroll 8
        for (int j = 0; j < 64; ++j) {
            int h = hc * 64 + j;
            a += dr[h] * Wd[(size_t)h * HID + k];
        }
        red[hc][kl] = a;
        __syncthreads();
        if (hc == 0) {
            float s = be[k] + bd[k];
#pragma unroll
            for (int c = 0; c < 8; ++c) s += red[c][kl];
            dproj[(size_t)b * HID + k] = s;
        }
    } else {
        // zero context region of d_out (16384 floats) + sumacc
        int bz = blk - 640;
        out[bz * 256 + t] = 0.f;
        if (bz == 0 && t < NB) sumacc[t] = 0.f;
    }
}

// ---------------------------------------------------------------------------
// K_main: 64 rows x 512 cols enc_proj via bf16 MFMA.
// B: async16 double-buffered LDS (dist-1, L2-resident source).
// A: register prefetch DISTANCE 2 (full-iteration in-flight, covers HBM
//    latency), cvt+ds_write one iter after load.
// Fused tanh*W_v -> score -> p=exp(score) -> partial expsum + partial context.
// ---------------------------------------------------------------------------
__global__ __launch_bounds__(256, 2)
void k_main(const float* __restrict__ E, const short* __restrict__ Bp,
            const float* __restrict__ dproj, const float* __restrict__ Wv,
            float* __restrict__ out, float* __restrict__ sumacc) {
    __shared__ short As[2][BM][BK + 8];   // 2 x 64 x 40 shorts = 10 KB
    __shared__ short Bs[2][BK * HID];     // 2 x 32 KB
    __shared__ float fbuf[640];
    __shared__ float pbuf[BM];

    const int tid  = threadIdx.x;
    const int wave = tid >> 6, lane = tid & 63;
    const int quad = lane >> 4, l15 = lane & 15;
    const int bid  = blockIdx.x;
    const int row0 = bid * BM;           // global row = b*4096 + s
    const int b    = bid >> 6;           // 64 blocks per batch

    f32x4 acc[4][8];
#pragma unroll
    for (int r = 0; r < 4; ++r)
#pragma unroll
        for (int c = 0; c < 8; ++c) acc[r][c] = (f32x4){0.f, 0.f, 0.f, 0.f};

    // A staging: thread t -> row t>>2, k-eighth t&3 (8 floats)
    const int arow = tid >> 2, akq = tid & 3;
    const float* aptr = E + (size_t)(row0 + arow) * HID + akq * 8;

    // PF2 register slots: A(j) lives in slot j&1
    float4 pa0[2], pa1[2];

    // ---- prologue: A(0),A(1) -> regs; B(0) -> Bs[0]; stage A(0) ----
    pa0[0] = *(const float4*)(aptr);
    pa1[0] = *(const float4*)(aptr + 4);
    pa0[1] = *(const float4*)(aptr + 32);
    pa1[1] = *(const float4*)(aptr + 36);
    {
        const short* bsrc = Bp;
#pragma unroll
        for (int i = 0; i < 8; ++i) {
            int off = (i * 4 + wave) * 512;
            async16(bsrc + off + lane * 8, &Bs[0][off]);
        }
        bf16x8 av;
        av[0] = f2bf(pa0[0].x); av[1] = f2bf(pa0[0].y); av[2] = f2bf(pa0[0].z); av[3] = f2bf(pa0[0].w);
        av[4] = f2bf(pa1[0].x); av[5] = f2bf(pa1[0].y); av[6] = f2bf(pa1[0].z); av[7] = f2bf(pa1[0].w);
        *(bf16x8*)&As[0][arow][akq * 8] = av;
    }

#pragma unroll
    for (int kc = 0; kc < NKC; ++kc) {
        const int cur = kc & 1, nxt = cur ^ 1;
        // drains: B(kc) asyncs into Bs[cur] (issued 1 full iter ago),
        // A(kc) ds_writes into As[cur], and PF2 A-loads (1 full iter in flight)
        __syncthreads();

        // ---- issue A(kc+2) global->reg into slot kc&1 (consumed next iter) ----
        {
            const int src = (kc + 2 < NKC) ? (kc + 2) : 0;   // clamp: harmless re-read
            pa0[kc & 1] = *(const float4*)(aptr + src * 32);
            pa1[kc & 1] = *(const float4*)(aptr + src * 32 + 4);
        }
        // ---- issue B(kc+1) async -> Bs[nxt] ----
        if (kc + 1 < NKC) {
            const short* bsrc = Bp + (size_t)(kc + 1) * 16384;
#pragma unroll
            for (int i = 0; i < 8; ++i) {
                int off = (i * 4 + wave) * 512;
                async16(bsrc + off + lane * 8, &Bs[nxt][off]);
            }
        }

        // ---- compute on buffer cur: wave tile 64 rows x 128 cols ----
        bf16x8 fa[4];
#pragma unroll
        for (int r = 0; r < 4; ++r) fa[r] = *(bf16x8*)&As[cur][r * 16 + l15][quad * 8];
#pragma unroll
        for (int c = 0; c < 8; ++c) {
            int nt = wave * 8 + c;
            bf16x8 fb = *(bf16x8*)&Bs[cur][(nt * 64 + lane) * 8];
#pragma unroll
            for (int r = 0; r < 4; ++r)
                acc[r][c] = __builtin_amdgcn_mfma_f32_16x16x32_bf16(fa[r], fb, acc[r][c], 0, 0, 0);
        }

        // ---- stage A(kc+1) (loaded LAST iter -> latency fully covered) ----
        if (kc + 1 < NKC) {
            float4 a0 = pa0[nxt], a1 = pa1[nxt];   // slot (kc+1)&1 == nxt
            bf16x8 av;
            av[0] = f2bf(a0.x); av[1] = f2bf(a0.y); av[2] = f2bf(a0.z); av[3] = f2bf(a0.w);
            av[4] = f2bf(a1.x); av[5] = f2bf(a1.y); av[6] = f2bf(a1.z); av[7] = f2bf(a1.w);
            *(bf16x8*)&As[nxt][arow][akq * 8] = av;
        }
    }

    // ---- epilogue a: score = sum_col tanh(acc + dproj[col]) * Wv[col] ----
    float part[4][4];
#pragma unroll
    for (int r = 0; r < 4; ++r)
#pragma unroll
        for (int g = 0; g < 4; ++g) part[r][g] = 0.f;
    const float* dp = dproj + (size_t)b * HID;
#pragma unroll
    for (int c = 0; c < 8; ++c) {
        int col = wave * 128 + c * 16 + l15;
        float dv = dp[col];
        float wv = Wv[col];
#pragma unroll
        for (int r = 0; r < 4; ++r)
#pragma unroll
            for (int g = 0; g < 4; ++g)
                part[r][g] += fast_tanh(acc[r][c][g] + dv) * wv;
    }
#pragma unroll
    for (int r = 0; r < 4; ++r)
#pragma unroll
        for (int g = 0; g < 4; ++g) {
            float v = part[r][g];
            v += __shfl_xor(v, 1); v += __shfl_xor(v, 2);
            v += __shfl_xor(v, 4); v += __shfl_xor(v, 8);
            part[r][g] = v;
        }
    if (l15 == 0) {
#pragma unroll
        for (int r = 0; r < 4; ++r)
#pragma unroll
            for (int g = 0; g < 4; ++g)
                fbuf[wave * 64 + r * 16 + quad * 4 + g] = part[r][g];
    }
    __syncthreads();
    if (tid < 64) {
        float s  = fbuf[tid] + fbuf[64 + tid] + fbuf[128 + tid] + fbuf[192 + tid];
        float pv = __expf(s);           // unnormalized; b_v cancels in softmax
        pbuf[tid] = pv;
        out[(size_t)NB * HID + row0 + tid] = pv;
        float t2 = pv;
        t2 += __shfl_xor(t2, 1);  t2 += __shfl_xor(t2, 2);  t2 += __shfl_xor(t2, 4);
        t2 += __shfl_xor(t2, 8);  t2 += __shfl_xor(t2, 16); t2 += __shfl_xor(t2, 32);
        if (tid == 0) atomicAdd(&sumacc[b], t2);
    }
    __syncthreads();

    // ---- epilogue b: partial context = sum_rows pv * E[row,:] (L2/L3-hot) ----
    const int hq = tid & 127, rh = tid >> 7;
    const float4* E4 = (const float4*)E;
    size_t cbase = (size_t)(row0 + rh * 32) * (HID / 4) + hq;
    float4 ca = {0.f, 0.f, 0.f, 0.f};
#pragma unroll 4
    for (int rr = 0; rr < 32; ++rr) {
        float w  = pbuf[rh * 32 + rr];
        float4 e = E4[cbase + (size_t)rr * (HID / 4)];
        ca.x += w * e.x; ca.y += w * e.y; ca.z += w * e.z; ca.w += w * e.w;
    }
    if (rh == 1) {
        fbuf[hq] = ca.x; fbuf[128 + hq] = ca.y; fbuf[256 + hq] = ca.z; fbuf[384 + hq] = ca.w;
    }
    __syncthreads();
    if (rh == 0) {
        ca.x += fbuf[hq]; ca.y += fbuf[128 + hq]; ca.z += fbuf[256 + hq]; ca.w += fbuf[384 + hq];
        float* cg = out + (size_t)b * HID + hq * 4;
        atomicAdd(cg + 0, ca.x); atomicAdd(cg + 1, ca.y);
        atomicAdd(cg + 2, ca.z); atomicAdd(cg + 3, ca.w);
    }
}

// ---------------------------------------------------------------------------
// K_finish: normalize in place: context /= sum, weights /= sum
// ---------------------------------------------------------------------------
__global__ void k_finish(float* __restrict__ out, const float* __restrict__ sumacc) {
    int b = blockIdx.x, t = threadIdx.x;
    float rs = 1.0f / sumacc[b];
    for (int i = t; i < HID; i += 256)
        out[(size_t)b * HID + i] *= rs;
    float* ow = out + (size_t)NB * HID + (size_t)b * SEQL;
    for (int i = t; i < SEQL; i += 256)
        ow[i] *= rs;
}

extern "C" void kernel_launch(void* const* d_in, const int* in_sizes, int n_in,
                              void* d_out, int out_size, void* d_ws, size_t ws_size,
                              hipStream_t stream) {
    const float* E   = (const float*)d_in[0];
    const float* dec = (const float*)d_in[1];
    const float* We  = (const float*)d_in[2];
    const float* be  = (const float*)d_in[3];
    const float* Wd  = (const float*)d_in[4];
    const float* bd  = (const float*)d_in[5];
    const float* Wv  = (const float*)d_in[6];
    // d_in[7] = b_v: uniform shift per score -> cancels in softmax
    float* out = (float*)d_out;
    char*  ws  = (char*)d_ws;
    short* Bp     = (short*)(ws + WS_BP);
    float* dproj  = (float*)(ws + WS_DPROJ);
    float* sumacc = (float*)(ws + WS_SUM);

    k_pre<<<704, 256, 0, stream>>>(We, Bp, dec, Wd, be, bd, dproj, out, sumacc);
    k_main<<<NBLK, 256, 0, stream>>>(E, Bp, dproj, Wv, out, sumacc);
    k_finish<<<NB, 256, 0, stream>>>(out, sumacc);
}